// Round 11
// baseline (386.343 us; speedup 1.0000x reference)
//
#include <hip/hip_runtime.h>
#include <hip/hip_cooperative_groups.h>

namespace cg = cooperative_groups;

#define kH  1024
#define kW  1024
#define kHW (kH * kW)
#define kSH 68
#define kSW 68
#define kD  8
#define kT3 (kSH * kSW * kD * kD * kD)
#define kNB 512           // persistent blocks: 2/CU on 256 CUs (safe margin)
// gridA (splat): per-cell TRANSPOSED layout idxT = (b<<6)+(r<<3)+g
// gridB (blur):  per-cell STANDARD  layout idx  = (r<<6)+(g<<3)+b

namespace {

// ======================= cooperative mega-kernel =======================
__global__ __launch_bounds__(256, 2)
void mega_kernel(const float* __restrict__ feat,
                 const float* __restrict__ inp,
                 float* __restrict__ out,
                 float* __restrict__ hdrF,
                 float* __restrict__ part,
                 float* __restrict__ gridA,
                 float* __restrict__ gridB) {
    cg::grid_group grid = cg::this_grid();
    __shared__ float S[6160];       // union: splat 3072 | blur 1728 | slice 6152

    // ---- Phase 1: min/max partials (512 blocks x 6 floats) ----
    {
        const float4* f4 = (const float4*)feat;
        float mn[3] = {1e30f, 1e30f, 1e30f}, mx[3] = {-1e30f, -1e30f, -1e30f};
        for (int c = blockIdx.x * 256 + threadIdx.x; c < kHW / 4; c += kNB * 256) {
            float4 q0 = f4[c * 3], q1 = f4[c * 3 + 1], q2 = f4[c * 3 + 2];
            mn[0] = fminf(mn[0], fminf(fminf(q0.x, q0.w), fminf(q1.z, q2.y)));
            mx[0] = fmaxf(mx[0], fmaxf(fmaxf(q0.x, q0.w), fmaxf(q1.z, q2.y)));
            mn[1] = fminf(mn[1], fminf(fminf(q0.y, q1.x), fminf(q1.w, q2.z)));
            mx[1] = fmaxf(mx[1], fmaxf(fmaxf(q0.y, q1.x), fmaxf(q1.w, q2.z)));
            mn[2] = fminf(mn[2], fminf(fminf(q0.z, q1.y), fminf(q2.x, q2.w)));
            mx[2] = fmaxf(mx[2], fmaxf(fmaxf(q0.z, q1.y), fmaxf(q2.x, q2.w)));
        }
        #pragma unroll
        for (int off = 32; off > 0; off >>= 1) {
            #pragma unroll
            for (int k = 0; k < 3; ++k) {
                mn[k] = fminf(mn[k], __shfl_down(mn[k], off, 64));
                mx[k] = fmaxf(mx[k], __shfl_down(mx[k], off, 64));
            }
        }
        int wave = threadIdx.x >> 6;
        if ((threadIdx.x & 63) == 0) {
            #pragma unroll
            for (int k = 0; k < 3; ++k) { S[wave * 3 + k] = mn[k]; S[12 + wave * 3 + k] = mx[k]; }
        }
        __syncthreads();
        if (threadIdx.x == 0) {
            #pragma unroll
            for (int k = 0; k < 3; ++k) {
                part[blockIdx.x * 6 + k]     = fminf(fminf(S[k], S[3 + k]), fminf(S[6 + k], S[9 + k]));
                part[blockIdx.x * 6 + 3 + k] = fmaxf(fmaxf(S[12 + k], S[15 + k]), fmaxf(S[18 + k], S[21 + k]));
            }
        }
        __syncthreads();
    }
    grid.sync();

    // ---- Phase 1b: block 0 reduces 512 partials + params ----
    if (blockIdx.x == 0) {
        int t = threadIdx.x;
        float mn[3] = {1e30f, 1e30f, 1e30f}, mx[3] = {-1e30f, -1e30f, -1e30f};
        #pragma unroll
        for (int j = 0; j < 2; ++j) {
            int idx = t + j * 256;
            #pragma unroll
            for (int k = 0; k < 3; ++k) {
                mn[k] = fminf(mn[k], part[idx * 6 + k]);
                mx[k] = fmaxf(mx[k], part[idx * 6 + 3 + k]);
            }
        }
        #pragma unroll
        for (int off = 32; off > 0; off >>= 1) {
            #pragma unroll
            for (int k = 0; k < 3; ++k) {
                mn[k] = fminf(mn[k], __shfl_down(mn[k], off, 64));
                mx[k] = fmaxf(mx[k], __shfl_down(mx[k], off, 64));
            }
        }
        int wave = t >> 6;
        if ((t & 63) == 0) {
            #pragma unroll
            for (int k = 0; k < 3; ++k) { S[wave * 3 + k] = mn[k]; S[12 + wave * 3 + k] = mx[k]; }
        }
        __syncthreads();
        if (t == 0) {
            int* ip = (int*)(hdrF + 8);
            #pragma unroll
            for (int k = 0; k < 3; ++k) {
                float bmn = fminf(fminf(S[k], S[3 + k]), fminf(S[6 + k], S[9 + k]));
                float bmx = fmaxf(fmaxf(S[12 + k], S[15 + k]), fmaxf(S[18 + k], S[21 + k]));
                float delta = bmx - bmn;                        // fp32 sub, like numpy
                int depth = (int)((double)delta / 0.25) + 1 + 4;
                if (depth > kD) depth = kD;
                if (depth < 1) depth = 1;
                hdrF[k] = bmn;
                ip[k] = depth;
            }
        }
    }
    grid.sync();

    float m0 = hdrF[0], m1 = hdrF[1], m2 = hdrF[2];
    const int* ip = (const int*)(hdrF + 8);
    int dr = ip[0], dg = ip[1], db = ip[2];

    // ---- Phase 2: splat (privatized per interior cell) ----
    {
        float* acc = S;            // 1536
        float* fS  = S + 1536;     // 768
        float* iS  = S + 2304;     // 768
        for (int cell = blockIdx.x; cell < 65 * 65; cell += kNB) {
            int iy = cell / 65, ix = cell % 65;
            int y0 = (iy == 0) ? 0 : 16 * iy - 8;
            int x0 = (ix == 0) ? 0 : 16 * ix - 8;
            int h = (iy == 0 || iy == 64) ? 8 : 16;
            int w = (ix == 0 || ix == 64) ? 8 : 16;

            for (int i = threadIdx.x; i < 1536; i += 256) acc[i] = 0.0f;

            int rowVec = (w * 3) >> 2;
            int nvec = h * rowVec;
            const float4* f4 = (const float4*)(feat + ((long)y0 * kW + x0) * 3);
            const float4* i4 = (const float4*)(inp  + ((long)y0 * kW + x0) * 3);
            for (int t = threadIdx.x; t < nvec; t += 256) {
                int row = t / rowVec, q = t - row * rowVec;
                ((float4*)fS)[row * rowVec + q] = f4[row * (kW * 3 / 4) + q];
                ((float4*)iS)[row * rowVec + q] = i4[row * (kW * 3 / 4) + q];
            }
            __syncthreads();

            int t = threadIdx.x;
            if (t < w * h) {
                int lx = t & (w - 1);
                int ly = (w == 16) ? (t >> 4) : (t >> 3);
                int o = (ly * w + lx) * 3;
                int sr  = (int)((fS[o + 0] - m0) * 4.0f + 0.5f) + 2;
                int sg2 = (int)((fS[o + 1] - m1) * 4.0f + 0.5f) + 2;
                int sb  = (int)((fS[o + 2] - m2) * 4.0f + 0.5f) + 2;
                int ci = (sr << 6) + (sg2 << 3) + sb;
                atomicAdd(&acc[ci],        iS[o + 0]);
                atomicAdd(&acc[512 + ci],  iS[o + 1]);
                atomicAdd(&acc[1024 + ci], iS[o + 2]);
            }
            __syncthreads();

            long base = ((long)((iy + 2) * kSW + (ix + 2))) << 9;
            for (int i = threadIdx.x; i < 512; i += 256) {
                int b = i >> 6, r = (i >> 3) & 7, g = i & 7;
                int s = (r << 6) + (g << 3) + b;
                gridA[base + i]            = acc[s];
                gridA[kT3 + base + i]      = acc[512 + s];
                gridA[2 * kT3 + base + i]  = acc[1024 + s];
            }
            __syncthreads();
        }
    }
    grid.sync();

    // ---- Phase 3: both blur iterations (per interior cell) ----
    {
        float* Sv = S;   // [ch][b(8) stride 72][rg(64)] = 1728
        for (int cell = blockIdx.x; cell < 65 * 65; cell += kNB) {
            int cy = cell / 65 + 2, cx = cell % 65 + 2;
            long cbase = ((long)(cy * kSW + cx)) << 9;
            {
                const float4* g4 = (const float4*)gridA;
                for (int i = threadIdx.x; i < 384; i += 256) {
                    int ch = i >> 7, i4 = i & 127;
                    float4 q = g4[(long)ch * (kT3 / 4) + (cbase >> 2) + i4];
                    int b = i4 >> 4;
                    int rg = ((i4 >> 1) & 7) * 8 + (i4 & 1) * 4;
                    *(float4*)&Sv[ch * 576 + b * 72 + rg] = q;
                }
            }
            __syncthreads();

            if (threadIdx.x < 192) {
                int ch = threadIdx.x >> 6;
                int rg = threadIdx.x & 63;
                int r = rg >> 3, g = rg & 7;

                float* Sc = Sv + ch * 576;
                auto SV = [&](int b, int l) -> float { return Sc[b * 72 + l]; };
                auto gsp = [&](int ccy, int ccx, int rr, int gg, int bb) -> float {
                    if (ccy < 2 || ccy > 66 || ccx < 2 || ccx > 66) return 0.0f;
                    return gridA[(long)ch * kT3 + (((long)(ccy * kSW + ccx)) << 9) + (bb << 6) + (rr << 3) + gg];
                };

                bool gI = (g >= 1) && (g <= dg - 2);
                bool rI = (r >= 1) && (r <= dr - 2);

                float v[8];
                #pragma unroll
                for (int b = 0; b < 8; ++b) v[b] = SV(b, rg);

                int eHi = db - 1;

                auto o1_end = [&](int e) -> float {
                    float Vm, Vp;
                    if (gI)      { Vm = SV(e, rg - 1); Vp = SV(e, rg + 1); }
                    else if (rI) { Vm = SV(e, rg - 8); Vp = SV(e, rg + 8); }
                    else         { Vm = gsp(cy, cx - 1, r, g, e); Vp = gsp(cy, cx + 1, r, g, e); }
                    return (Vm + Vp + 2.0f * SV(e, rg)) * 0.25f;
                };
                float o1_lo = o1_end(0);
                float o1_hi = o1_end(eHi);

                float o1[8];
                #pragma unroll
                for (int b = 0; b < 8; ++b) {
                    float iv = 0.0f;
                    if (b >= 1 && b <= 6) iv = ((v[b - 1] + v[b + 1]) + 2.0f * v[b]) * 0.25f;
                    o1[b] = (b >= 1 && b <= db - 2) ? iv : (b == 0 ? o1_lo : (b == eHi ? o1_hi : 0.0f));
                }

                auto out1_in = [&](int r2, int g2, int e) -> float {
                    int l2 = (r2 << 3) + g2;
                    float C = SV(e, l2);
                    float Nm, Np;
                    if (g2 >= 1 && g2 <= dg - 2)      { Nm = SV(e, l2 - 1); Np = SV(e, l2 + 1); }
                    else if (r2 >= 1 && r2 <= dr - 2) { Nm = SV(e, l2 - 8); Np = SV(e, l2 + 8); }
                    else { Nm = gsp(cy, cx - 1, r2, g2, e); Np = gsp(cy, cx + 1, r2, g2, e); }
                    return (Nm + Np + 2.0f * C) * 0.25f;
                };
                auto out1_x = [&](int cx2, int e) -> float {
                    float C = gsp(cy, cx2, r, g, e);
                    float Nm, Np;
                    if (cx2 >= 1 && cx2 <= kSW - 2) { Nm = gsp(cy, cx2 - 1, r, g, e); Np = gsp(cy, cx2 + 1, r, g, e); }
                    else                            { Nm = gsp(cy - 1, cx2, r, g, e); Np = gsp(cy + 1, cx2, r, g, e); }
                    return (Nm + Np + 2.0f * C) * 0.25f;
                };
                auto o2_end = [&](int e, float o1e) -> float {
                    float Xm, Xp;
                    if (gI)      { Xm = out1_in(r, g - 1, e); Xp = out1_in(r, g + 1, e); }
                    else if (rI) { Xm = out1_in(r - 1, g, e); Xp = out1_in(r + 1, g, e); }
                    else         { Xm = out1_x(cx - 1, e);    Xp = out1_x(cx + 1, e); }
                    return (Xm + Xp + 2.0f * o1e) * 0.25f;
                };
                float o2_lo = o2_end(0, o1_lo);
                float o2_hi = o2_end(eHi, o1_hi);

                float o2[8];
                #pragma unroll
                for (int b = 0; b < 8; ++b) {
                    float iv = 0.0f;
                    if (b >= 1 && b <= 6) iv = ((o1[b - 1] + o1[b + 1]) + 2.0f * o1[b]) * 0.25f;
                    o2[b] = (b >= 1 && b <= db - 2) ? iv : (b == 0 ? o2_lo : (b == eHi ? o2_hi : 0.0f));
                }

                float* dp = gridB + (long)ch * kT3 + cbase + (rg << 3);
                *(float4*)dp       = make_float4(o2[0], o2[1], o2[2], o2[3]);
                *(float4*)(dp + 4) = make_float4(o2[4], o2[5], o2[6], o2[7]);
            }
            __syncthreads();
        }
    }
    grid.sync();

    // ---- Phase 4: slice (per 16x16 tile) ----
    {
        float* sg = S;
        for (int tile = blockIdx.x; tile < 64 * 64; tile += kNB) {
            int ty = tile >> 6, tx = tile & 63;
            {
                const float4* g4 = (const float4*)gridB;
                float4* s4 = (float4*)sg;
                #pragma unroll
                for (int it = 0; it < 2; ++it) {
                    int i = threadIdx.x + it * 256;
                    int cell = i >> 7;
                    int ci4 = i & 127;
                    int cy = ty + 2 + (cell >> 1), cx = tx + 2 + (cell & 1);
                    long cbase4 = ((long)(cy * kSW + cx)) << 7;
                    #pragma unroll
                    for (int ch = 0; ch < 3; ++ch)
                        s4[ch * 512 + i] = g4[(long)ch * (kT3 / 4) + cbase4 + ci4];
                }
            }
            __syncthreads();

            int lx = threadIdx.x & 15, ly = threadIdx.x >> 4;
            int y = (ty << 4) + ly, x = (tx << 4) + lx;
            int p = (y << 10) + x;

            float ya = (float)ly * 0.0625f;
            float xa = (float)lx * 0.0625f;

            int d3[3] = {dr, dg, db};
            float mm[3] = {m0, m1, m2};
            int li[3], ri[3];
            float al[3];
            #pragma unroll
            for (int c = 0; c < 3; ++c) {
                float v0 = feat[p * 3 + c] - mm[c];
                float sv = v0 * 4.0f + 2.0f;
                int l = (int)sv;
                int dm = d3[c] - 1;
                l = l < 0 ? 0 : (l > dm ? dm : l);
                int rr = l + 1 > dm ? dm : l + 1;
                li[c] = l; ri[c] = rr; al[c] = sv - (float)l;
            }

            float spw[4];
            {
                float wy[2] = {1.0f - ya, ya};
                float wx[2] = {1.0f - xa, xa};
                spw[0] = wy[0] * wx[0]; spw[1] = wy[0] * wx[1];
                spw[2] = wy[1] * wx[0]; spw[3] = wy[1] * wx[1];
            }
            int rs[2] = {li[0], ri[0]}; float wrr[2] = {1.0f - al[0], al[0]};
            int gs[2] = {li[1], ri[1]}; float wgg[2] = {1.0f - al[1], al[1]};
            int bq = li[2];
            float aeff = (ri[2] > li[2]) ? al[2] : 0.0f;

            float acc0 = 0.0f, acc1 = 0.0f, acc2 = 0.0f;
            #pragma unroll
            for (int k = 0; k < 4; ++k) {
                #pragma unroll
                for (int cr = 0; cr < 2; ++cr)
                #pragma unroll
                for (int cg = 0; cg < 2; ++cg) {
                    int si = (k << 9) + (rs[cr] << 6) + (gs[cg] << 3) + bq;
                    float w = spw[k] * wrr[cr] * wgg[cg];
                    float a0 = sg[si],        a1 = sg[si + 1];
                    float b0 = sg[2048 + si], b1 = sg[2048 + si + 1];
                    float c0 = sg[4096 + si], c1 = sg[4096 + si + 1];
                    acc0 += w * (a0 + aeff * (a1 - a0));
                    acc1 += w * (b0 + aeff * (b1 - b0));
                    acc2 += w * (c0 + aeff * (c1 - c0));
                }
            }
            out[p * 3 + 0] = acc0;
            out[p * 3 + 1] = acc1;
            out[p * 3 + 2] = acc2;
            __syncthreads();
        }
    }
}

// ======================= fallback: proven R9 pipeline =======================
__global__ void fb_minmax(const float* __restrict__ feat, float* __restrict__ part) {
    const float4* f4 = (const float4*)feat;
    float mn[3] = {1e30f, 1e30f, 1e30f}, mx[3] = {-1e30f, -1e30f, -1e30f};
    int tid = blockIdx.x * blockDim.x + threadIdx.x;
    int stride = gridDim.x * blockDim.x;
    for (int c = tid; c < kHW / 4; c += stride) {
        float4 q0 = f4[c * 3], q1 = f4[c * 3 + 1], q2 = f4[c * 3 + 2];
        mn[0] = fminf(mn[0], fminf(fminf(q0.x, q0.w), fminf(q1.z, q2.y)));
        mx[0] = fmaxf(mx[0], fmaxf(fmaxf(q0.x, q0.w), fmaxf(q1.z, q2.y)));
        mn[1] = fminf(mn[1], fminf(fminf(q0.y, q1.x), fminf(q1.w, q2.z)));
        mx[1] = fmaxf(mx[1], fmaxf(fmaxf(q0.y, q1.x), fmaxf(q1.w, q2.z)));
        mn[2] = fminf(mn[2], fminf(fminf(q0.z, q1.y), fminf(q2.x, q2.w)));
        mx[2] = fmaxf(mx[2], fmaxf(fmaxf(q0.z, q1.y), fmaxf(q2.x, q2.w)));
    }
    #pragma unroll
    for (int off = 32; off > 0; off >>= 1) {
        #pragma unroll
        for (int c = 0; c < 3; ++c) {
            mn[c] = fminf(mn[c], __shfl_down(mn[c], off, 64));
            mx[c] = fmaxf(mx[c], __shfl_down(mx[c], off, 64));
        }
    }
    __shared__ float smn[4][3], smx[4][3];
    int wave = threadIdx.x >> 6;
    if ((threadIdx.x & 63) == 0) {
        #pragma unroll
        for (int c = 0; c < 3; ++c) { smn[wave][c] = mn[c]; smx[wave][c] = mx[c]; }
    }
    __syncthreads();
    if (threadIdx.x == 0) {
        #pragma unroll
        for (int c = 0; c < 3; ++c) {
            part[blockIdx.x * 6 + c]     = fminf(fminf(smn[0][c], smn[1][c]), fminf(smn[2][c], smn[3][c]));
            part[blockIdx.x * 6 + 3 + c] = fmaxf(fmaxf(smx[0][c], smx[1][c]), fmaxf(smx[2][c], smx[3][c]));
        }
    }
}

__global__ void fb_params(const float* __restrict__ part, float* __restrict__ hdrF) {
    int t = threadIdx.x;
    float mn[3], mx[3];
    #pragma unroll
    for (int c = 0; c < 3; ++c) { mn[c] = part[t * 6 + c]; mx[c] = part[t * 6 + 3 + c]; }
    #pragma unroll
    for (int off = 32; off > 0; off >>= 1) {
        #pragma unroll
        for (int c = 0; c < 3; ++c) {
            mn[c] = fminf(mn[c], __shfl_down(mn[c], off, 64));
            mx[c] = fmaxf(mx[c], __shfl_down(mx[c], off, 64));
        }
    }
    __shared__ float smn[4][3], smx[4][3];
    int wave = t >> 6;
    if ((t & 63) == 0) {
        #pragma unroll
        for (int c = 0; c < 3; ++c) { smn[wave][c] = mn[c]; smx[wave][c] = mx[c]; }
    }
    __syncthreads();
    if (t == 0) {
        int* ip = (int*)(hdrF + 8);
        #pragma unroll
        for (int c = 0; c < 3; ++c) {
            float bmn = fminf(fminf(smn[0][c], smn[1][c]), fminf(smn[2][c], smn[3][c]));
            float bmx = fmaxf(fmaxf(smx[0][c], smx[1][c]), fmaxf(smx[2][c], smx[3][c]));
            float delta = bmx - bmn;
            int depth = (int)((double)delta / 0.25) + 1 + 4;
            if (depth > kD) depth = kD;
            if (depth < 1) depth = 1;
            hdrF[c] = bmn;
            ip[c] = depth;
        }
    }
}

__global__ __launch_bounds__(256) void fb_splat(const float* __restrict__ feat,
                                                const float* __restrict__ inp,
                                                const float* __restrict__ hdrF,
                                                float* __restrict__ grid) {
    int ix = blockIdx.x, iy = blockIdx.y;
    int y0 = (iy == 0) ? 0 : 16 * iy - 8;
    int x0 = (ix == 0) ? 0 : 16 * ix - 8;
    int h = (iy == 0 || iy == 64) ? 8 : 16;
    int w = (ix == 0 || ix == 64) ? 8 : 16;

    __shared__ float acc[3 * 512];
    __shared__ float fS[16 * 48], iS[16 * 48];
    for (int i = threadIdx.x; i < 3 * 512; i += 256) acc[i] = 0.0f;

    int rowVec = (w * 3) >> 2;
    int nvec = h * rowVec;
    const float4* f4 = (const float4*)(feat + ((long)y0 * kW + x0) * 3);
    const float4* i4 = (const float4*)(inp  + ((long)y0 * kW + x0) * 3);
    for (int t = threadIdx.x; t < nvec; t += 256) {
        int row = t / rowVec, q = t - row * rowVec;
        ((float4*)fS)[row * rowVec + q] = f4[row * (kW * 3 / 4) + q];
        ((float4*)iS)[row * rowVec + q] = i4[row * (kW * 3 / 4) + q];
    }
    __syncthreads();

    int t = threadIdx.x;
    if (t < w * h) {
        int lx = t & (w - 1);
        int ly = (w == 16) ? (t >> 4) : (t >> 3);
        int o = (ly * w + lx) * 3;
        int sr = (int)((fS[o + 0] - hdrF[0]) * 4.0f + 0.5f) + 2;
        int sg = (int)((fS[o + 1] - hdrF[1]) * 4.0f + 0.5f) + 2;
        int sb = (int)((fS[o + 2] - hdrF[2]) * 4.0f + 0.5f) + 2;
        int ci = (sr << 6) + (sg << 3) + sb;
        atomicAdd(&acc[ci],        iS[o + 0]);
        atomicAdd(&acc[512 + ci],  iS[o + 1]);
        atomicAdd(&acc[1024 + ci], iS[o + 2]);
    }
    __syncthreads();

    long base = ((long)((iy + 2) * kSW + (ix + 2))) << 9;
    for (int i = threadIdx.x; i < 512; i += 256) {
        int b = i >> 6, r = (i >> 3) & 7, g = i & 7;
        int s = (r << 6) + (g << 3) + b;
        grid[base + i]            = acc[s];
        grid[kT3 + base + i]      = acc[512 + s];
        grid[2 * kT3 + base + i]  = acc[1024 + s];
    }
}

__global__ __launch_bounds__(192) void fb_blur2(float* __restrict__ dst,
                                                const float* __restrict__ src,
                                                const float* __restrict__ hdrF) {
    int cx = blockIdx.x + 2, cy = blockIdx.y + 2;
    const int* ip = (const int*)(hdrF + 8);
    int dr = ip[0], dg = ip[1], db = ip[2];

    __shared__ float Sv[3 * 576];
    long cbase = ((long)(cy * kSW + cx)) << 9;

    {
        const float4* g4 = (const float4*)src;
        for (int i = threadIdx.x; i < 384; i += 192) {
            int ch = i >> 7, i4 = i & 127;
            float4 q = g4[(long)ch * (kT3 / 4) + (cbase >> 2) + i4];
            int b = i4 >> 4;
            int rg = ((i4 >> 1) & 7) * 8 + (i4 & 1) * 4;
            *(float4*)&Sv[ch * 576 + b * 72 + rg] = q;
        }
    }
    __syncthreads();

    int ch = threadIdx.x >> 6;
    int rg = threadIdx.x & 63;
    int r = rg >> 3, g = rg & 7;

    float* S = Sv + ch * 576;
    auto SV = [&](int b, int l) -> float { return S[b * 72 + l]; };
    auto gsp = [&](int ccy, int ccx, int rr, int gg, int bb) -> float {
        if (ccy < 2 || ccy > 66 || ccx < 2 || ccx > 66) return 0.0f;
        return src[(long)ch * kT3 + (((long)(ccy * kSW + ccx)) << 9) + (bb << 6) + (rr << 3) + gg];
    };

    bool gI = (g >= 1) && (g <= dg - 2);
    bool rI = (r >= 1) && (r <= dr - 2);

    float v[8];
    #pragma unroll
    for (int b = 0; b < 8; ++b) v[b] = SV(b, rg);

    int eHi = db - 1;

    auto o1_end = [&](int e) -> float {
        float Vm, Vp;
        if (gI)      { Vm = SV(e, rg - 1); Vp = SV(e, rg + 1); }
        else if (rI) { Vm = SV(e, rg - 8); Vp = SV(e, rg + 8); }
        else         { Vm = gsp(cy, cx - 1, r, g, e); Vp = gsp(cy, cx + 1, r, g, e); }
        return (Vm + Vp + 2.0f * SV(e, rg)) * 0.25f;
    };
    float o1_lo = o1_end(0);
    float o1_hi = o1_end(eHi);

    float o1[8];
    #pragma unroll
    for (int b = 0; b < 8; ++b) {
        float iv = 0.0f;
        if (b >= 1 && b <= 6) iv = ((v[b - 1] + v[b + 1]) + 2.0f * v[b]) * 0.25f;
        o1[b] = (b >= 1 && b <= db - 2) ? iv : (b == 0 ? o1_lo : (b == eHi ? o1_hi : 0.0f));
    }

    auto out1_in = [&](int r2, int g2, int e) -> float {
        int l2 = (r2 << 3) + g2;
        float C = SV(e, l2);
        float Nm, Np;
        if (g2 >= 1 && g2 <= dg - 2)      { Nm = SV(e, l2 - 1); Np = SV(e, l2 + 1); }
        else if (r2 >= 1 && r2 <= dr - 2) { Nm = SV(e, l2 - 8); Np = SV(e, l2 + 8); }
        else { Nm = gsp(cy, cx - 1, r2, g2, e); Np = gsp(cy, cx + 1, r2, g2, e); }
        return (Nm + Np + 2.0f * C) * 0.25f;
    };
    auto out1_x = [&](int cx2, int e) -> float {
        float C = gsp(cy, cx2, r, g, e);
        float Nm, Np;
        if (cx2 >= 1 && cx2 <= kSW - 2) { Nm = gsp(cy, cx2 - 1, r, g, e); Np = gsp(cy, cx2 + 1, r, g, e); }
        else                            { Nm = gsp(cy - 1, cx2, r, g, e); Np = gsp(cy + 1, cx2, r, g, e); }
        return (Nm + Np + 2.0f * C) * 0.25f;
    };
    auto o2_end = [&](int e, float o1e) -> float {
        float Xm, Xp;
        if (gI)      { Xm = out1_in(r, g - 1, e); Xp = out1_in(r, g + 1, e); }
        else if (rI) { Xm = out1_in(r - 1, g, e); Xp = out1_in(r + 1, g, e); }
        else         { Xm = out1_x(cx - 1, e);    Xp = out1_x(cx + 1, e); }
        return (Xm + Xp + 2.0f * o1e) * 0.25f;
    };
    float o2_lo = o2_end(0, o1_lo);
    float o2_hi = o2_end(eHi, o1_hi);

    float o2[8];
    #pragma unroll
    for (int b = 0; b < 8; ++b) {
        float iv = 0.0f;
        if (b >= 1 && b <= 6) iv = ((o1[b - 1] + o1[b + 1]) + 2.0f * o1[b]) * 0.25f;
        o2[b] = (b >= 1 && b <= db - 2) ? iv : (b == 0 ? o2_lo : (b == eHi ? o2_hi : 0.0f));
    }

    float* dp = dst + (long)ch * kT3 + cbase + (rg << 3);
    *(float4*)dp       = make_float4(o2[0], o2[1], o2[2], o2[3]);
    *(float4*)(dp + 4) = make_float4(o2[4], o2[5], o2[6], o2[7]);
}

__global__ __launch_bounds__(256) void fb_slice(const float* __restrict__ feat,
                                                const float* __restrict__ hdrF,
                                                const float* __restrict__ grid,
                                                float* __restrict__ out) {
    __shared__ float sg[3 * 4 * 512 + 8];
    int tx = blockIdx.x, ty = blockIdx.y;

    {
        const float4* g4 = (const float4*)grid;
        float4* s4 = (float4*)sg;
        #pragma unroll
        for (int it = 0; it < 2; ++it) {
            int i = threadIdx.x + it * 256;
            int cell = i >> 7;
            int ci4 = i & 127;
            int cy = ty + 2 + (cell >> 1), cx = tx + 2 + (cell & 1);
            long cbase4 = ((long)(cy * kSW + cx)) << 7;
            #pragma unroll
            for (int ch = 0; ch < 3; ++ch)
                s4[ch * 512 + i] = g4[(long)ch * (kT3 / 4) + cbase4 + ci4];
        }
    }
    __syncthreads();

    const int* ip = (const int*)(hdrF + 8);
    int d3[3] = {ip[0], ip[1], ip[2]};
    int lx = threadIdx.x & 15, ly = threadIdx.x >> 4;
    int y = (ty << 4) + ly, x = (tx << 4) + lx;
    int p = (y << 10) + x;

    float ya = (float)ly * 0.0625f;
    float xa = (float)lx * 0.0625f;

    int li[3], ri[3];
    float al[3];
    #pragma unroll
    for (int c = 0; c < 3; ++c) {
        float v0 = feat[p * 3 + c] - hdrF[c];
        float sv = v0 * 4.0f + 2.0f;
        int l = (int)sv;
        int dm = d3[c] - 1;
        l = l < 0 ? 0 : (l > dm ? dm : l);
        int rr = l + 1 > dm ? dm : l + 1;
        li[c] = l; ri[c] = rr; al[c] = sv - (float)l;
    }

    float spw[4];
    {
        float wy[2] = {1.0f - ya, ya};
        float wx[2] = {1.0f - xa, xa};
        spw[0] = wy[0] * wx[0]; spw[1] = wy[0] * wx[1];
        spw[2] = wy[1] * wx[0]; spw[3] = wy[1] * wx[1];
    }
    int rs[2] = {li[0], ri[0]}; float wrr[2] = {1.0f - al[0], al[0]};
    int gs[2] = {li[1], ri[1]}; float wgg[2] = {1.0f - al[1], al[1]};
    int bq = li[2];
    float aeff = (ri[2] > li[2]) ? al[2] : 0.0f;

    float acc0 = 0.0f, acc1 = 0.0f, acc2 = 0.0f;
    #pragma unroll
    for (int k = 0; k < 4; ++k) {
        #pragma unroll
        for (int cr = 0; cr < 2; ++cr)
        #pragma unroll
        for (int cg = 0; cg < 2; ++cg) {
            int si = (k << 9) + (rs[cr] << 6) + (gs[cg] << 3) + bq;
            float w = spw[k] * wrr[cr] * wgg[cg];
            float a0 = sg[si],        a1 = sg[si + 1];
            float b0 = sg[2048 + si], b1 = sg[2048 + si + 1];
            float c0 = sg[4096 + si], c1 = sg[4096 + si + 1];
            acc0 += w * (a0 + aeff * (a1 - a0));
            acc1 += w * (b0 + aeff * (b1 - b0));
            acc2 += w * (c0 + aeff * (c1 - c0));
        }
    }
    out[p * 3 + 0] = acc0;
    out[p * 3 + 1] = acc1;
    out[p * 3 + 2] = acc2;
}

}  // namespace

extern "C" void kernel_launch(void* const* d_in, const int* in_sizes, int n_in,
                              void* d_out, int out_size, void* d_ws, size_t ws_size,
                              hipStream_t stream) {
    const float* feat = (const float*)d_in[0];
    const float* inp  = (const float*)d_in[1];
    float* out = (float*)d_out;

    float* hdrF  = (float*)d_ws;
    float* part  = (float*)((char*)d_ws + 16384);       // 512 x 6 floats (mega) / 256 x 6 (fallback)
    float* gridA = (float*)((char*)d_ws + 65536);       // splat, transposed cells
    float* gridB = gridA + 3 * (size_t)kT3;             // blurred, standard cells

    void* args[] = {(void*)&feat, (void*)&inp, (void*)&out,
                    (void*)&hdrF, (void*)&part, (void*)&gridA, (void*)&gridB};
    hipError_t err = hipLaunchCooperativeKernel((const void*)mega_kernel, dim3(kNB),
                                                dim3(256), args, 0, stream);
    if (err != hipSuccess) {
        // fallback: proven 5-kernel pipeline (R9)
        fb_minmax<<<256, 256, 0, stream>>>(feat, part);
        fb_params<<<1, 256, 0, stream>>>(part, hdrF);
        fb_splat<<<dim3(65, 65), 256, 0, stream>>>(feat, inp, hdrF, gridA);
        fb_blur2<<<dim3(65, 65), 192, 0, stream>>>(gridB, gridA, hdrF);
        fb_slice<<<dim3(64, 64), 256, 0, stream>>>(feat, hdrF, gridB, out);
    }
}

// Round 12
// 163.613 us; speedup vs baseline: 2.3613x; 2.3613x over previous
//
#include <hip/hip_runtime.h>
#include <hip/hip_fp16.h>

namespace {

constexpr int kH  = 1024;
constexpr int kW  = 1024;
constexpr int kHW = kH * kW;
constexpr int kSH = 68;           // int(1023/16)+1+2*2
constexpr int kSW = 68;
constexpr int kD  = 8;            // max depth; features uniform [0,1) -> depth <= 8
constexpr int kT3 = kSH * kSW * kD * kD * kD;   // grid cells per channel
// gridA (splat, __half): per-cell TRANSPOSED layout idxT = (b<<6)+(r<<3)+g
// gridB (blur,  __half): per-cell STANDARD  layout idx  = (r<<6)+(g<<3)+b

// Per-block inline reduction of the 256x6 minmax partials -> mins + depths.
// Every consumer block does this itself (removes the params dispatch).
template <int NT>
__device__ inline void load_params(const float* __restrict__ part,
                                   float mOut[3], int dOut[3]) {
    __shared__ float pm[NT / 64][6];
    float mn[3] = {1e30f, 1e30f, 1e30f}, mx[3] = {-1e30f, -1e30f, -1e30f};
    for (int idx = threadIdx.x; idx < 256; idx += NT) {
        #pragma unroll
        for (int c = 0; c < 3; ++c) {
            mn[c] = fminf(mn[c], part[idx * 6 + c]);
            mx[c] = fmaxf(mx[c], part[idx * 6 + 3 + c]);
        }
    }
    #pragma unroll
    for (int off = 32; off > 0; off >>= 1) {
        #pragma unroll
        for (int c = 0; c < 3; ++c) {
            mn[c] = fminf(mn[c], __shfl_down(mn[c], off, 64));
            mx[c] = fmaxf(mx[c], __shfl_down(mx[c], off, 64));
        }
    }
    int wave = threadIdx.x >> 6;
    if ((threadIdx.x & 63) == 0) {
        #pragma unroll
        for (int c = 0; c < 3; ++c) { pm[wave][c] = mn[c]; pm[wave][3 + c] = mx[c]; }
    }
    __syncthreads();
    #pragma unroll
    for (int c = 0; c < 3; ++c) {
        float bmn = pm[0][c], bmx = pm[0][3 + c];
        #pragma unroll
        for (int w = 1; w < NT / 64; ++w) {
            bmn = fminf(bmn, pm[w][c]);
            bmx = fmaxf(bmx, pm[w][3 + c]);
        }
        float delta = bmx - bmn;                        // fp32 sub, like numpy
        int depth = (int)((double)delta / 0.25) + 1 + 4;
        depth = depth > kD ? kD : (depth < 1 ? 1 : depth);
        mOut[c] = bmn;
        dOut[c] = depth;
    }
}

__global__ void minmax_kernel(const float* __restrict__ feat, float* __restrict__ part) {
    // feat = 262144 chunks of 3 float4 (4 pixels); channel pattern per chunk:
    // q0={0,1,2,0} q1={1,2,0,1} q2={2,0,1,2}
    const float4* f4 = (const float4*)feat;
    float mn[3] = {1e30f, 1e30f, 1e30f}, mx[3] = {-1e30f, -1e30f, -1e30f};
    int tid = blockIdx.x * blockDim.x + threadIdx.x;
    int stride = gridDim.x * blockDim.x;
    for (int c = tid; c < kHW / 4; c += stride) {
        float4 q0 = f4[c * 3], q1 = f4[c * 3 + 1], q2 = f4[c * 3 + 2];
        mn[0] = fminf(mn[0], fminf(fminf(q0.x, q0.w), fminf(q1.z, q2.y)));
        mx[0] = fmaxf(mx[0], fmaxf(fmaxf(q0.x, q0.w), fmaxf(q1.z, q2.y)));
        mn[1] = fminf(mn[1], fminf(fminf(q0.y, q1.x), fminf(q1.w, q2.z)));
        mx[1] = fmaxf(mx[1], fmaxf(fmaxf(q0.y, q1.x), fmaxf(q1.w, q2.z)));
        mn[2] = fminf(mn[2], fminf(fminf(q0.z, q1.y), fminf(q2.x, q2.w)));
        mx[2] = fmaxf(mx[2], fmaxf(fmaxf(q0.z, q1.y), fmaxf(q2.x, q2.w)));
    }
    #pragma unroll
    for (int off = 32; off > 0; off >>= 1) {
        #pragma unroll
        for (int c = 0; c < 3; ++c) {
            mn[c] = fminf(mn[c], __shfl_down(mn[c], off, 64));
            mx[c] = fmaxf(mx[c], __shfl_down(mx[c], off, 64));
        }
    }
    __shared__ float smn[4][3], smx[4][3];
    int wave = threadIdx.x >> 6;
    if ((threadIdx.x & 63) == 0) {
        #pragma unroll
        for (int c = 0; c < 3; ++c) { smn[wave][c] = mn[c]; smx[wave][c] = mx[c]; }
    }
    __syncthreads();
    if (threadIdx.x == 0) {
        #pragma unroll
        for (int c = 0; c < 3; ++c) {
            part[blockIdx.x * 6 + c]     = fminf(fminf(smn[0][c], smn[1][c]), fminf(smn[2][c], smn[3][c]));
            part[blockIdx.x * 6 + 3 + c] = fmaxf(fmaxf(smx[0][c], smx[1][c]), fmaxf(smx[2][c], smx[3][c]));
        }
    }
}

// Privatized splat: one block per INTERIOR cell [2,66]^2; LDS histogram in
// standard order, written out TRANSPOSED as packed half2 pairs. Zero atomics.
__global__ __launch_bounds__(256) void splat_kernel(const float* __restrict__ feat,
                                                    const float* __restrict__ inp,
                                                    const float* __restrict__ part,
                                                    __half* __restrict__ grid) {
    float mm[3]; int dd[3];
    load_params<256>(part, mm, dd);

    int ix = blockIdx.x, iy = blockIdx.y;          // band index 0..64
    int y0 = (iy == 0) ? 0 : 16 * iy - 8;
    int x0 = (ix == 0) ? 0 : 16 * ix - 8;
    int h = (iy == 0 || iy == 64) ? 8 : 16;
    int w = (ix == 0 || ix == 64) ? 8 : 16;

    __shared__ float acc[3 * 512];
    __shared__ float fS[16 * 48], iS[16 * 48];
    for (int i = threadIdx.x; i < 3 * 512; i += 256) acc[i] = 0.0f;

    int rowVec = (w * 3) >> 2;                     // float4 per row: 12 or 6
    int nvec = h * rowVec;
    const float4* f4 = (const float4*)(feat + ((long)y0 * kW + x0) * 3);
    const float4* i4 = (const float4*)(inp  + ((long)y0 * kW + x0) * 3);
    for (int t = threadIdx.x; t < nvec; t += 256) {
        int row = t / rowVec, q = t - row * rowVec;
        ((float4*)fS)[row * rowVec + q] = f4[row * (kW * 3 / 4) + q];
        ((float4*)iS)[row * rowVec + q] = i4[row * (kW * 3 / 4) + q];
    }
    __syncthreads();

    int t = threadIdx.x;
    if (t < w * h) {
        int lx = t & (w - 1);
        int ly = (w == 16) ? (t >> 4) : (t >> 3);
        int o = (ly * w + lx) * 3;
        int sr = (int)((fS[o + 0] - mm[0]) * 4.0f + 0.5f) + 2;   // /0.25 == *4 exact
        int sg = (int)((fS[o + 1] - mm[1]) * 4.0f + 0.5f) + 2;
        int sb = (int)((fS[o + 2] - mm[2]) * 4.0f + 0.5f) + 2;
        int ci = (sr << 6) + (sg << 3) + sb;
        atomicAdd(&acc[ci],        iS[o + 0]);
        atomicAdd(&acc[512 + ci],  iS[o + 1]);
        atomicAdd(&acc[1024 + ci], iS[o + 2]);
    }
    __syncthreads();

    long base = ((long)((iy + 2) * kSW + (ix + 2))) << 9;   // in halves
    for (int i = threadIdx.x; i < 768; i += 256) {
        int ch = i >> 8, p = i & 255;
        // half2 pair covers transposed idxT = 2p, 2p+1 (g even, g+1)
        int g = (2 * p) & 7, r = ((2 * p) >> 3) & 7, b = (2 * p) >> 6;
        int s0 = (r << 6) + (g << 3) + b;
        __half2 hv = __halves2half2(__float2half_rn(acc[ch * 512 + s0]),
                                    __float2half_rn(acc[ch * 512 + s0 + 8]));
        ((__half2*)(grid + (long)ch * kT3 + base))[p] = hv;
    }
}

// Both _convn outer-iterations, LDS-resident per spatial cell (R6/R9 algo),
// fp16 grids. Stencil math fp32 in LDS (stride-72 pad), output packed to
// 8 halves = one 16B store per thread.
__global__ __launch_bounds__(192) void blur2_kernel(__half* __restrict__ dst,
                                                    const __half* __restrict__ src,
                                                    const float* __restrict__ part) {
    float mm[3]; int dd[3];
    load_params<192>(part, mm, dd);
    int dr = dd[0], dg = dd[1], db = dd[2];

    int cx = blockIdx.x + 2, cy = blockIdx.y + 2;   // [2,66]
    __shared__ float Sv[3 * 576];   // [ch][b(8) stride 72][rg(64)]
    long cbase = ((long)(cy * kSW + cx)) << 9;      // in halves

    {
        // one float4 = 8 halves = transposed idxT (b,r fixed, g=0..7)
        for (int i = threadIdx.x; i < 192; i += 192) {
            int ch = i >> 6, i8 = i & 63;
            float4 q = ((const float4*)(src + (long)ch * kT3 + cbase))[i8];
            int b = i8 >> 3, r = i8 & 7;
            float2 f0 = __half22float2(*(__half2*)&q.x);
            float2 f1 = __half22float2(*((__half2*)&q.x + 1));
            float2 f2 = __half22float2(*(__half2*)&q.z);
            float2 f3 = __half22float2(*((__half2*)&q.z + 1));
            float* S = Sv + ch * 576 + b * 72 + r * 8;
            S[0] = f0.x; S[1] = f0.y; S[2] = f1.x; S[3] = f1.y;
            S[4] = f2.x; S[5] = f2.y; S[6] = f3.x; S[7] = f3.y;
        }
    }
    __syncthreads();

    int ch = threadIdx.x >> 6;
    int rg = threadIdx.x & 63;
    int r = rg >> 3, g = rg & 7;

    float* S = Sv + ch * 576;
    auto SV = [&](int b, int l) -> float { return S[b * 72 + l]; };
    auto gsp = [&](int ccy, int ccx, int rr, int gg, int bb) -> float {
        if (ccy < 2 || ccy > 66 || ccx < 2 || ccx > 66) return 0.0f;
        return __half2float(src[(long)ch * kT3 + (((long)(ccy * kSW + ccx)) << 9) +
                                (bb << 6) + (rr << 3) + gg]);
    };

    bool gI = (g >= 1) && (g <= dg - 2);
    bool rI = (r >= 1) && (r <= dr - 2);

    float v[8];
    #pragma unroll
    for (int b = 0; b < 8; ++b) v[b] = SV(b, rg);

    int eHi = db - 1;

    auto o1_end = [&](int e) -> float {
        float Vm, Vp;
        if (gI)      { Vm = SV(e, rg - 1); Vp = SV(e, rg + 1); }
        else if (rI) { Vm = SV(e, rg - 8); Vp = SV(e, rg + 8); }
        else         { Vm = gsp(cy, cx - 1, r, g, e); Vp = gsp(cy, cx + 1, r, g, e); }
        return (Vm + Vp + 2.0f * SV(e, rg)) * 0.25f;
    };
    float o1_lo = o1_end(0);
    float o1_hi = o1_end(eHi);

    float o1[8];
    #pragma unroll
    for (int b = 0; b < 8; ++b) {
        float iv = 0.0f;
        if (b >= 1 && b <= 6) iv = ((v[b - 1] + v[b + 1]) + 2.0f * v[b]) * 0.25f;
        o1[b] = (b >= 1 && b <= db - 2) ? iv : (b == 0 ? o1_lo : (b == eHi ? o1_hi : 0.0f));
    }

    auto out1_in = [&](int r2, int g2, int e) -> float {
        int l2 = (r2 << 3) + g2;
        float C = SV(e, l2);
        float Nm, Np;
        if (g2 >= 1 && g2 <= dg - 2)      { Nm = SV(e, l2 - 1); Np = SV(e, l2 + 1); }
        else if (r2 >= 1 && r2 <= dr - 2) { Nm = SV(e, l2 - 8); Np = SV(e, l2 + 8); }
        else { Nm = gsp(cy, cx - 1, r2, g2, e); Np = gsp(cy, cx + 1, r2, g2, e); }
        return (Nm + Np + 2.0f * C) * 0.25f;
    };
    auto out1_x = [&](int cx2, int e) -> float {
        float C = gsp(cy, cx2, r, g, e);
        float Nm, Np;
        if (cx2 >= 1 && cx2 <= kSW - 2) { Nm = gsp(cy, cx2 - 1, r, g, e); Np = gsp(cy, cx2 + 1, r, g, e); }
        else                            { Nm = gsp(cy - 1, cx2, r, g, e); Np = gsp(cy + 1, cx2, r, g, e); }
        return (Nm + Np + 2.0f * C) * 0.25f;
    };
    auto o2_end = [&](int e, float o1e) -> float {
        float Xm, Xp;
        if (gI)      { Xm = out1_in(r, g - 1, e); Xp = out1_in(r, g + 1, e); }
        else if (rI) { Xm = out1_in(r - 1, g, e); Xp = out1_in(r + 1, g, e); }
        else         { Xm = out1_x(cx - 1, e);    Xp = out1_x(cx + 1, e); }
        return (Xm + Xp + 2.0f * o1e) * 0.25f;
    };
    float o2_lo = o2_end(0, o1_lo);
    float o2_hi = o2_end(eHi, o1_hi);

    float o2[8];
    #pragma unroll
    for (int b = 0; b < 8; ++b) {
        float iv = 0.0f;
        if (b >= 1 && b <= 6) iv = ((o1[b - 1] + o1[b + 1]) + 2.0f * o1[b]) * 0.25f;
        o2[b] = (b >= 1 && b <= db - 2) ? iv : (b == 0 ? o2_lo : (b == eHi ? o2_hi : 0.0f));
    }

    // standard layout: this thread's 8 b-values contiguous at rg*8 -> one 16B store
    __half2 h0 = __halves2half2(__float2half_rn(o2[0]), __float2half_rn(o2[1]));
    __half2 h1 = __halves2half2(__float2half_rn(o2[2]), __float2half_rn(o2[3]));
    __half2 h2 = __halves2half2(__float2half_rn(o2[4]), __float2half_rn(o2[5]));
    __half2 h3 = __halves2half2(__float2half_rn(o2[6]), __float2half_rn(o2[7]));
    float4 pack;
    *(__half2*)&pack.x = h0; *((__half2*)&pack.x + 1) = h1;
    *(__half2*)&pack.z = h2; *((__half2*)&pack.z + 1) = h3;
    ((float4*)(dst + (long)ch * kT3 + cbase))[rg] = pack;
}

// LDS-staged slice (R9 structure, fp16 gridB): one block per 16x16 tile,
// stage 4 cells x 512 x 3ch into fp32 LDS (24 KB); adjacent b-pair gathers
// (ds_read2-mergeable) + arithmetic b-lerp.
__global__ __launch_bounds__(256) void slice_kernel(const float* __restrict__ feat,
                                                    const float* __restrict__ part,
                                                    const __half* __restrict__ gridB,
                                                    float* __restrict__ out) {
    float mm[3]; int dd[3];
    load_params<256>(part, mm, dd);

    __shared__ float sg[3 * 4 * 512 + 8];   // [ch][cell][512], pad for b=7 pair
    int tx = blockIdx.x, ty = blockIdx.y;   // 64 x 64 tiles

    {
        for (int j = 0; j < 3; ++j) {
            int id = threadIdx.x + j * 256;           // [0, 768): cell x ch x line
            int cell = id / 192;
            int rem = id - cell * 192;
            int ch = rem >> 6, line = rem & 63;
            int cy = ty + 2 + (cell >> 1), cx = tx + 2 + (cell & 1);
            float4 q = ((const float4*)(gridB + (long)ch * kT3 +
                                        (((long)(cy * kSW + cx)) << 9)))[line];
            float2 f0 = __half22float2(*(__half2*)&q.x);
            float2 f1 = __half22float2(*((__half2*)&q.x + 1));
            float2 f2 = __half22float2(*(__half2*)&q.z);
            float2 f3 = __half22float2(*((__half2*)&q.z + 1));
            float* d = sg + ch * 2048 + cell * 512 + line * 8;
            ((float4*)d)[0] = make_float4(f0.x, f0.y, f1.x, f1.y);
            ((float4*)d)[1] = make_float4(f2.x, f2.y, f3.x, f3.y);
        }
    }
    __syncthreads();

    int lx = threadIdx.x & 15, ly = threadIdx.x >> 4;
    int y = (ty << 4) + ly, x = (tx << 4) + lx;
    int p = (y << 10) + x;

    float ya = (float)ly * 0.0625f;   // exact fractional part of y/16
    float xa = (float)lx * 0.0625f;

    int li[3], ri[3];
    float al[3];
    #pragma unroll
    for (int c = 0; c < 3; ++c) {
        float v0 = feat[p * 3 + c] - mm[c];
        float sv = v0 * 4.0f + 2.0f;
        int l = (int)sv;
        int dm = dd[c] - 1;
        l = l < 0 ? 0 : (l > dm ? dm : l);
        int rr = l + 1 > dm ? dm : l + 1;
        li[c] = l; ri[c] = rr; al[c] = sv - (float)l;
    }

    float spw[4];
    {
        float wy[2] = {1.0f - ya, ya};
        float wx[2] = {1.0f - xa, xa};
        spw[0] = wy[0] * wx[0]; spw[1] = wy[0] * wx[1];
        spw[2] = wy[1] * wx[0]; spw[3] = wy[1] * wx[1];
    }
    int rs[2] = {li[0], ri[0]}; float wrr[2] = {1.0f - al[0], al[0]};
    int gs[2] = {li[1], ri[1]}; float wgg[2] = {1.0f - al[1], al[1]};
    int bq = li[2];
    float aeff = (ri[2] > li[2]) ? al[2] : 0.0f;

    float acc0 = 0.0f, acc1 = 0.0f, acc2 = 0.0f;
    #pragma unroll
    for (int k = 0; k < 4; ++k) {
        #pragma unroll
        for (int cr = 0; cr < 2; ++cr)
        #pragma unroll
        for (int cg = 0; cg < 2; ++cg) {
            int si = (k << 9) + (rs[cr] << 6) + (gs[cg] << 3) + bq;
            float w = spw[k] * wrr[cr] * wgg[cg];
            float a0 = sg[si],        a1 = sg[si + 1];
            float b0 = sg[2048 + si], b1 = sg[2048 + si + 1];
            float c0 = sg[4096 + si], c1 = sg[4096 + si + 1];
            acc0 += w * (a0 + aeff * (a1 - a0));
            acc1 += w * (b0 + aeff * (b1 - b0));
            acc2 += w * (c0 + aeff * (c1 - c0));
        }
    }
    out[p * 3 + 0] = acc0;
    out[p * 3 + 1] = acc1;
    out[p * 3 + 2] = acc2;
}

}  // namespace

extern "C" void kernel_launch(void* const* d_in, const int* in_sizes, int n_in,
                              void* d_out, int out_size, void* d_ws, size_t ws_size,
                              hipStream_t stream) {
    const float* feat = (const float*)d_in[0];
    const float* inp  = (const float*)d_in[1];
    float* out = (float*)d_out;

    float*  part  = (float*)((char*)d_ws + 1024);       // 256 x 6 floats
    __half* gridA = (__half*)((char*)d_ws + 65536);     // splat, transposed, fp16
    __half* gridB = gridA + 3 * (size_t)kT3;            // blurred, standard, fp16

    minmax_kernel<<<256, 256, 0, stream>>>(feat, part);
    splat_kernel<<<dim3(65, 65), 256, 0, stream>>>(feat, inp, part, gridA);
    blur2_kernel<<<dim3(65, 65), 192, 0, stream>>>(gridB, gridA, part);
    slice_kernel<<<dim3(64, 64), 256, 0, stream>>>(feat, part, gridB, out);
}

// Round 13
// 142.401 us; speedup vs baseline: 2.7131x; 1.1490x over previous
//
#include <hip/hip_runtime.h>

namespace {

constexpr int kH  = 1024;
constexpr int kW  = 1024;
constexpr int kHW = kH * kW;
constexpr int kSH = 68;           // int(1023/16)+1+2*2
constexpr int kSW = 68;
constexpr int kD  = 8;            // max depth; features uniform [0,1) -> depth <= 8
constexpr int kT3 = kSH * kSW * kD * kD * kD;   // grid cells per channel
// gridA (splat): per-cell TRANSPOSED layout idxT = (b<<6)+(r<<3)+g
// gridB (blur):  per-cell STANDARD  layout idx  = (r<<6)+(g<<3)+b

__global__ void minmax_kernel(const float* __restrict__ feat, float* __restrict__ part) {
    // feat = 262144 chunks of 3 float4 (4 pixels); channel pattern per chunk:
    // q0={0,1,2,0} q1={1,2,0,1} q2={2,0,1,2}
    const float4* f4 = (const float4*)feat;
    float mn[3] = {1e30f, 1e30f, 1e30f}, mx[3] = {-1e30f, -1e30f, -1e30f};
    int tid = blockIdx.x * blockDim.x + threadIdx.x;
    int stride = gridDim.x * blockDim.x;
    for (int c = tid; c < kHW / 4; c += stride) {
        float4 q0 = f4[c * 3], q1 = f4[c * 3 + 1], q2 = f4[c * 3 + 2];
        mn[0] = fminf(mn[0], fminf(fminf(q0.x, q0.w), fminf(q1.z, q2.y)));
        mx[0] = fmaxf(mx[0], fmaxf(fmaxf(q0.x, q0.w), fmaxf(q1.z, q2.y)));
        mn[1] = fminf(mn[1], fminf(fminf(q0.y, q1.x), fminf(q1.w, q2.z)));
        mx[1] = fmaxf(mx[1], fmaxf(fmaxf(q0.y, q1.x), fmaxf(q1.w, q2.z)));
        mn[2] = fminf(mn[2], fminf(fminf(q0.z, q1.y), fminf(q2.x, q2.w)));
        mx[2] = fmaxf(mx[2], fmaxf(fmaxf(q0.z, q1.y), fmaxf(q2.x, q2.w)));
    }
    #pragma unroll
    for (int off = 32; off > 0; off >>= 1) {
        #pragma unroll
        for (int c = 0; c < 3; ++c) {
            mn[c] = fminf(mn[c], __shfl_down(mn[c], off, 64));
            mx[c] = fmaxf(mx[c], __shfl_down(mx[c], off, 64));
        }
    }
    __shared__ float smn[4][3], smx[4][3];
    int wave = threadIdx.x >> 6;
    if ((threadIdx.x & 63) == 0) {
        #pragma unroll
        for (int c = 0; c < 3; ++c) { smn[wave][c] = mn[c]; smx[wave][c] = mx[c]; }
    }
    __syncthreads();
    if (threadIdx.x == 0) {
        #pragma unroll
        for (int c = 0; c < 3; ++c) {
            part[blockIdx.x * 6 + c]     = fminf(fminf(smn[0][c], smn[1][c]), fminf(smn[2][c], smn[3][c]));
            part[blockIdx.x * 6 + 3 + c] = fmaxf(fmaxf(smx[0][c], smx[1][c]), fmaxf(smx[2][c], smx[3][c]));
        }
    }
}

__global__ void params_kernel(const float* __restrict__ part, float* __restrict__ hdrF) {
    int t = threadIdx.x;   // 256 threads, one per partial
    float mn[3], mx[3];
    #pragma unroll
    for (int c = 0; c < 3; ++c) { mn[c] = part[t * 6 + c]; mx[c] = part[t * 6 + 3 + c]; }
    #pragma unroll
    for (int off = 32; off > 0; off >>= 1) {
        #pragma unroll
        for (int c = 0; c < 3; ++c) {
            mn[c] = fminf(mn[c], __shfl_down(mn[c], off, 64));
            mx[c] = fmaxf(mx[c], __shfl_down(mx[c], off, 64));
        }
    }
    __shared__ float smn[4][3], smx[4][3];
    int wave = t >> 6;
    if ((t & 63) == 0) {
        #pragma unroll
        for (int c = 0; c < 3; ++c) { smn[wave][c] = mn[c]; smx[wave][c] = mx[c]; }
    }
    __syncthreads();
    if (t == 0) {
        int* ip = (int*)(hdrF + 8);
        #pragma unroll
        for (int c = 0; c < 3; ++c) {
            float bmn = fminf(fminf(smn[0][c], smn[1][c]), fminf(smn[2][c], smn[3][c]));
            float bmx = fmaxf(fmaxf(smx[0][c], smx[1][c]), fmaxf(smx[2][c], smx[3][c]));
            float delta = bmx - bmn;                        // fp32 sub, like numpy
            int depth = (int)((double)delta / 0.25) + 1 + 4;
            if (depth > kD) depth = kD;
            if (depth < 1) depth = 1;
            hdrF[c] = bmn;
            ip[c] = depth;
        }
    }
}

// Privatized splat: one block per INTERIOR cell [2,66]^2; LDS histogram in
// standard (r<<6|g<<3|b) order, written out in TRANSPOSED order (b<<6|r<<3|g)
// so blur2's staging is a straight vector copy. Zero global atomics.
__global__ __launch_bounds__(256) void splat_kernel(const float* __restrict__ feat,
                                                    const float* __restrict__ inp,
                                                    const float* __restrict__ hdrF,
                                                    float* __restrict__ grid) {
    int ix = blockIdx.x, iy = blockIdx.y;          // band index 0..64
    int y0 = (iy == 0) ? 0 : 16 * iy - 8;
    int x0 = (ix == 0) ? 0 : 16 * ix - 8;
    int h = (iy == 0 || iy == 64) ? 8 : 16;
    int w = (ix == 0 || ix == 64) ? 8 : 16;

    __shared__ float acc[3 * 512];
    __shared__ float fS[16 * 48], iS[16 * 48];
    for (int i = threadIdx.x; i < 3 * 512; i += 256) acc[i] = 0.0f;

    int rowVec = (w * 3) >> 2;                     // float4 per row: 12 or 6
    int nvec = h * rowVec;
    const float4* f4 = (const float4*)(feat + ((long)y0 * kW + x0) * 3);
    const float4* i4 = (const float4*)(inp  + ((long)y0 * kW + x0) * 3);
    for (int t = threadIdx.x; t < nvec; t += 256) {
        int row = t / rowVec, q = t - row * rowVec;
        ((float4*)fS)[row * rowVec + q] = f4[row * (kW * 3 / 4) + q];
        ((float4*)iS)[row * rowVec + q] = i4[row * (kW * 3 / 4) + q];
    }
    __syncthreads();

    int t = threadIdx.x;
    if (t < w * h) {
        int lx = t & (w - 1);
        int ly = (w == 16) ? (t >> 4) : (t >> 3);
        int o = (ly * w + lx) * 3;
        float v0 = fS[o + 0] - hdrF[0];
        float v1 = fS[o + 1] - hdrF[1];
        float v2 = fS[o + 2] - hdrF[2];
        int sr = (int)(v0 * 4.0f + 0.5f) + 2;   // /0.25 == *4 exact
        int sg = (int)(v1 * 4.0f + 0.5f) + 2;
        int sb = (int)(v2 * 4.0f + 0.5f) + 2;
        int ci = (sr << 6) + (sg << 3) + sb;
        atomicAdd(&acc[ci],        iS[o + 0]);
        atomicAdd(&acc[512 + ci],  iS[o + 1]);
        atomicAdd(&acc[1024 + ci], iS[o + 2]);
    }
    __syncthreads();

    long base = ((long)((iy + 2) * kSW + (ix + 2))) << 9;
    for (int i = threadIdx.x; i < 512; i += 256) {
        // output position i in transposed layout (b<<6|r<<3|g)
        int b = i >> 6, r = (i >> 3) & 7, g = i & 7;
        int s = (r << 6) + (g << 3) + b;
        grid[base + i]            = acc[s];
        grid[kT3 + base + i]      = acc[512 + s];
        grid[2 * kT3 + base + i]  = acc[1024 + s];
    }
}

// Both _convn outer-iterations, LDS-resident per spatial cell (R6 algorithm).
// gridA is transposed -> staging is a straight float4 copy into the padded
// stencil layout Sv[ch][b (stride 72)][r*8+g]. Output written straight from
// registers to gridB in STANDARD layout (each thread's 8 b-values contiguous).
__global__ __launch_bounds__(192) void blur2_kernel(float* __restrict__ dst,
                                                    const float* __restrict__ src,
                                                    const float* __restrict__ hdrF) {
    int cx = blockIdx.x + 2, cy = blockIdx.y + 2;   // [2,66]
    const int* ip = (const int*)(hdrF + 8);
    int dr = ip[0], dg = ip[1], db = ip[2];

    __shared__ float Sv[3 * 576];   // [ch][b(8) stride 72][rg(64)]
    long cbase = ((long)(cy * kSW + cx)) << 9;

    {
        const float4* g4 = (const float4*)src;
        for (int i = threadIdx.x; i < 384; i += 192) {
            int ch = i >> 7, i4 = i & 127;
            float4 q = g4[(long)ch * (kT3 / 4) + (cbase >> 2) + i4];
            int b = i4 >> 4;
            int rg = ((i4 >> 1) & 7) * 8 + (i4 & 1) * 4;
            *(float4*)&Sv[ch * 576 + b * 72 + rg] = q;
        }
    }
    __syncthreads();

    int ch = threadIdx.x >> 6;
    int rg = threadIdx.x & 63;
    int r = rg >> 3, g = rg & 7;

    float* S = Sv + ch * 576;
    auto SV = [&](int b, int l) -> float { return S[b * 72 + l]; };
    auto gsp = [&](int ccy, int ccx, int rr, int gg, int bb) -> float {
        if (ccy < 2 || ccy > 66 || ccx < 2 || ccx > 66) return 0.0f;
        return src[(long)ch * kT3 + (((long)(ccy * kSW + ccx)) << 9) + (bb << 6) + (rr << 3) + gg];
    };

    bool gI = (g >= 1) && (g <= dg - 2);
    bool rI = (r >= 1) && (r <= dr - 2);

    float v[8];
    #pragma unroll
    for (int b = 0; b < 8; ++b) v[b] = SV(b, rg);

    int eHi = db - 1;

    auto o1_end = [&](int e) -> float {
        float Vm, Vp;
        if (gI)      { Vm = SV(e, rg - 1); Vp = SV(e, rg + 1); }
        else if (rI) { Vm = SV(e, rg - 8); Vp = SV(e, rg + 8); }
        else         { Vm = gsp(cy, cx - 1, r, g, e); Vp = gsp(cy, cx + 1, r, g, e); }
        return (Vm + Vp + 2.0f * SV(e, rg)) * 0.25f;
    };
    float o1_lo = o1_end(0);
    float o1_hi = o1_end(eHi);

    float o1[8];
    #pragma unroll
    for (int b = 0; b < 8; ++b) {
        float iv = 0.0f;
        if (b >= 1 && b <= 6) iv = ((v[b - 1] + v[b + 1]) + 2.0f * v[b]) * 0.25f;
        o1[b] = (b >= 1 && b <= db - 2) ? iv : (b == 0 ? o1_lo : (b == eHi ? o1_hi : 0.0f));
    }

    auto out1_in = [&](int r2, int g2, int e) -> float {
        int l2 = (r2 << 3) + g2;
        float C = SV(e, l2);
        float Nm, Np;
        if (g2 >= 1 && g2 <= dg - 2)      { Nm = SV(e, l2 - 1); Np = SV(e, l2 + 1); }
        else if (r2 >= 1 && r2 <= dr - 2) { Nm = SV(e, l2 - 8); Np = SV(e, l2 + 8); }
        else { Nm = gsp(cy, cx - 1, r2, g2, e); Np = gsp(cy, cx + 1, r2, g2, e); }
        return (Nm + Np + 2.0f * C) * 0.25f;
    };
    auto out1_x = [&](int cx2, int e) -> float {
        float C = gsp(cy, cx2, r, g, e);
        float Nm, Np;
        if (cx2 >= 1 && cx2 <= kSW - 2) { Nm = gsp(cy, cx2 - 1, r, g, e); Np = gsp(cy, cx2 + 1, r, g, e); }
        else                            { Nm = gsp(cy - 1, cx2, r, g, e); Np = gsp(cy + 1, cx2, r, g, e); }
        return (Nm + Np + 2.0f * C) * 0.25f;
    };
    auto o2_end = [&](int e, float o1e) -> float {
        float Xm, Xp;
        if (gI)      { Xm = out1_in(r, g - 1, e); Xp = out1_in(r, g + 1, e); }
        else if (rI) { Xm = out1_in(r - 1, g, e); Xp = out1_in(r + 1, g, e); }
        else         { Xm = out1_x(cx - 1, e);    Xp = out1_x(cx + 1, e); }
        return (Xm + Xp + 2.0f * o1e) * 0.25f;
    };
    float o2_lo = o2_end(0, o1_lo);
    float o2_hi = o2_end(eHi, o1_hi);

    float o2[8];
    #pragma unroll
    for (int b = 0; b < 8; ++b) {
        float iv = 0.0f;
        if (b >= 1 && b <= 6) iv = ((o1[b - 1] + o1[b + 1]) + 2.0f * o1[b]) * 0.25f;
        o2[b] = (b >= 1 && b <= db - 2) ? iv : (b == 0 ? o2_lo : (b == eHi ? o2_hi : 0.0f));
    }

    // standard layout: this thread's 8 b-values are contiguous at rg*8
    float* dp = dst + (long)ch * kT3 + cbase + (rg << 3);
    *(float4*)dp       = make_float4(o2[0], o2[1], o2[2], o2[3]);
    *(float4*)(dp + 4) = make_float4(o2[4], o2[5], o2[6], o2[7]);
}

// LDS-staged slice (R9 + coalesced feat/out): one block per 16x16 pixel tile.
// Grid cells staged as before (24 KB); feat tile staged via 192 float4 loads;
// results collected in an LDS out-tile and written via 192 float4 stores —
// eliminates the 12B-stride scalar global loads/stores (3x12-line splinter
// per wave instruction).
__global__ __launch_bounds__(256) void slice_kernel(const float* __restrict__ feat,
                                                    const float* __restrict__ hdrF,
                                                    const float* __restrict__ grid,
                                                    float* __restrict__ out) {
    __shared__ float sg[3 * 4 * 512 + 8];   // [ch][cell][512], pad for b=7 pair
    __shared__ float fS[768];               // feat tile [ly][lx*3+c]
    __shared__ float oS[768];               // out  tile [ly][lx*3+c]
    int tx = blockIdx.x, ty = blockIdx.y;   // 64 x 64 tiles

    {
        const float4* g4 = (const float4*)grid;
        float4* s4 = (float4*)sg;
        #pragma unroll
        for (int it = 0; it < 2; ++it) {
            int i = threadIdx.x + it * 256;       // float4 index within a channel plane [0,512)
            int cell = i >> 7;                    // 0..3 = (dy<<1)|dx
            int ci4 = i & 127;
            int cy = ty + 2 + (cell >> 1), cx = tx + 2 + (cell & 1);
            long cbase4 = ((long)(cy * kSW + cx)) << 7;   // 128 float4 per cell
            #pragma unroll
            for (int ch = 0; ch < 3; ++ch)
                s4[ch * 512 + i] = g4[(long)ch * (kT3 / 4) + cbase4 + ci4];
        }
        // feat tile: 16 rows x 12 float4 (48 floats) per row, aligned
        if (threadIdx.x < 192) {
            int row = threadIdx.x / 12, q = threadIdx.x - row * 12;
            ((float4*)fS)[row * 12 + q] =
                ((const float4*)feat)[((long)((ty << 4) + row)) * 768 + tx * 12 + q];
        }
    }
    __syncthreads();

    const int* ip = (const int*)(hdrF + 8);
    int d3[3] = {ip[0], ip[1], ip[2]};
    int lx = threadIdx.x & 15, ly = threadIdx.x >> 4;

    float ya = (float)ly * 0.0625f;   // exact fractional part of y/16
    float xa = (float)lx * 0.0625f;

    int li[3], ri[3];
    float al[3];
    int fo = (ly * 16 + lx) * 3;
    #pragma unroll
    for (int c = 0; c < 3; ++c) {
        float v0 = fS[fo + c] - hdrF[c];
        float sv = v0 * 4.0f + 2.0f;
        int l = (int)sv;
        int dm = d3[c] - 1;
        l = l < 0 ? 0 : (l > dm ? dm : l);
        int rr = l + 1 > dm ? dm : l + 1;
        li[c] = l; ri[c] = rr; al[c] = sv - (float)l;
    }

    float spw[4];
    {
        float wy[2] = {1.0f - ya, ya};
        float wx[2] = {1.0f - xa, xa};
        spw[0] = wy[0] * wx[0]; spw[1] = wy[0] * wx[1];
        spw[2] = wy[1] * wx[0]; spw[3] = wy[1] * wx[1];
    }
    int rs[2] = {li[0], ri[0]}; float wrr[2] = {1.0f - al[0], al[0]};
    int gs[2] = {li[1], ri[1]}; float wgg[2] = {1.0f - al[1], al[1]};
    int bq = li[2];
    float aeff = (ri[2] > li[2]) ? al[2] : 0.0f;

    float acc0 = 0.0f, acc1 = 0.0f, acc2 = 0.0f;
    #pragma unroll
    for (int k = 0; k < 4; ++k) {
        #pragma unroll
        for (int cr = 0; cr < 2; ++cr)
        #pragma unroll
        for (int cg = 0; cg < 2; ++cg) {
            int si = (k << 9) + (rs[cr] << 6) + (gs[cg] << 3) + bq;
            float w = spw[k] * wrr[cr] * wgg[cg];
            float a0 = sg[si],        a1 = sg[si + 1];
            float b0 = sg[2048 + si], b1 = sg[2048 + si + 1];
            float c0 = sg[4096 + si], c1 = sg[4096 + si + 1];
            acc0 += w * (a0 + aeff * (a1 - a0));
            acc1 += w * (b0 + aeff * (b1 - b0));
            acc2 += w * (c0 + aeff * (c1 - c0));
        }
    }
    oS[fo + 0] = acc0;
    oS[fo + 1] = acc1;
    oS[fo + 2] = acc2;
    __syncthreads();

    if (threadIdx.x < 192) {
        int row = threadIdx.x / 12, q = threadIdx.x - row * 12;
        ((float4*)out)[((long)((ty << 4) + row)) * 768 + tx * 12 + q] =
            ((float4*)oS)[row * 12 + q];
    }
}

}  // namespace

extern "C" void kernel_launch(void* const* d_in, const int* in_sizes, int n_in,
                              void* d_out, int out_size, void* d_ws, size_t ws_size,
                              hipStream_t stream) {
    const float* feat = (const float*)d_in[0];
    const float* inp  = (const float*)d_in[1];
    float* out = (float*)d_out;

    float* hdrF  = (float*)d_ws;
    float* part  = (float*)((char*)d_ws + 1024);       // 256 x 6 floats
    float* gridA = (float*)((char*)d_ws + 8192);       // splat, transposed cells
    float* gridB = gridA + 3 * (size_t)kT3;            // blurred, standard cells

    minmax_kernel<<<256, 256, 0, stream>>>(feat, part);
    params_kernel<<<1, 256, 0, stream>>>(part, hdrF);

    splat_kernel<<<dim3(65, 65), 256, 0, stream>>>(feat, inp, hdrF, gridA);
    blur2_kernel<<<dim3(65, 65), 192, 0, stream>>>(gridB, gridA, hdrF);
    slice_kernel<<<dim3(64, 64), 256, 0, stream>>>(feat, hdrF, gridB, out);
}